// Round 3
// baseline (140.553 us; speedup 1.0000x reference)
//
#include <hip/hip_runtime.h>

// SGAN_PoolingNet: pooled[i] = max_j relu( relu([hidden[j], (ends[j]-ends[i])@We+be] @ W1 + b1) @ W2 + b2 )
// Collapse: y_lin[i,j,:] = A[j,:] - U[i,:]
//   A[j,k] = hidden[j]@W1[0:64,k] + ends[j]@M2[:,k] + b1[k] + be@W1[64:80,k]   (f32 math, stored f16)
//   U[i,k] = ends[i]@M2[:,k],  M2 = We @ W1[64:80,:]  (2x128, f32)
// R6: counters showed latency/occupancy-bound (MfmaUtil 12% = MFMA floor already; 40% of cycles
//     neither pipe issues; Occupancy 22% = 2 waves/SIMD, reg-capped: 84 VGPR + 64 AGPR bfrag ~ 148
//     -> 64-granule 192 -> 2/SIMD). Fixes:
//  (a) f16 datapath (A, W2T, U stored f16; mfma_f32_16x16x32_f16 same rate as bf16): sub+relu runs
//      on PACKED pairs via v_pk_add_f16 neg + v_pk_max_f16 -> 2 instr/dword vs 7 (no unpack/cvt).
//      Also improves precision (f16 10-bit mantissa vs bf16 8-bit).
//  (b) 2(j)x2(n) wave split: each wave holds a 32-col B panel (32 VGPR, not 64) and 32 j-tiles.
//      Working set ~120 regs -> __launch_bounds__(256,4) -> 4 waves/SIMD, full grid resident.
//  (c) unroll-2 double-buffer A prefetch (no copies, no per-iter branch).

#define N_AG 1024

typedef __attribute__((ext_vector_type(8))) _Float16 half8;      // 8 f16 = 4 VGPR (MFMA A/B frag)
typedef __attribute__((ext_vector_type(4))) float floatx4;       // MFMA C/D frag
typedef __attribute__((ext_vector_type(4))) unsigned int uintx4; // 4 packed f16 pairs

__device__ __forceinline__ unsigned short f2h(float f) {
  return __builtin_bit_cast(unsigned short, (_Float16)f);   // RNE
}

// d = max(a - u, 0) elementwise on packed f16 pairs: 2 VALU instrs, no unpack.
__device__ __forceinline__ unsigned pk_sub_relu(unsigned a, unsigned u) {
  unsigned d;
  asm("v_pk_add_f16 %0, %1, %2 neg_lo:[0,1] neg_hi:[0,1]\n\t"
      "v_pk_max_f16 %0, %0, 0"
      : "=v"(d) : "v"(a), "v"(u));
  return d;
}

// ---- prep (fused): block j computes A[j]; block 0 writes M2; blocks 0..31 write W2T ----
__global__ __launch_bounds__(128) void prep_all(
    const float* __restrict__ hidden,  // (1,1024,64)
    const float* __restrict__ track,   // (1024,8,2)
    const float* __restrict__ We,      // (2,16)
    const float* __restrict__ be,      // (16)
    const float* __restrict__ W1,      // (80,128)
    const float* __restrict__ b1,      // (128)
    const float* __restrict__ W2,      // (128,64)
    unsigned short* __restrict__ Ah,   // (1024,128) f16
    float* __restrict__ M2f,           // (2,128) f32
    unsigned short* __restrict__ W2T)  // (64,128) f16
{
  int j = blockIdx.x;
  int k = threadIdx.x;   // 0..127
  __shared__ float hj[64];
  if (k < 64) hj[k] = hidden[j * 64 + k];
  __syncthreads();
  float e0 = track[j * 16 + 14];
  float e1 = track[j * 16 + 15];
  float m20 = 0.f, m21 = 0.f, cb = b1[k];
#pragma unroll
  for (int t = 0; t < 16; ++t) {
    float w1v = W1[(64 + t) * 128 + k];
    m20 += We[t] * w1v;
    m21 += We[16 + t] * w1v;
    cb  += be[t] * w1v;
  }
  float acc = e0 * m20 + e1 * m21 + cb;
#pragma unroll 16
  for (int t = 0; t < 64; ++t) acc += hj[t] * W1[t * 128 + k];
  // non-temporal: every pool block on every XCD streams Ah next dispatch.
  __builtin_nontemporal_store(f2h(acc), &Ah[j * 128 + k]);

  if (j == 0) {           // m20/m21 are exactly M2[0][k], M2[1][k]
    M2f[k]       = m20;
    M2f[128 + k] = m21;
  }
  if (j < 32) {           // W2T[n][c] = f16(W2[c][n]); 32 blocks x 256 entries
#pragma unroll
    for (int q = 0; q < 2; ++q) {
      int idx = j * 256 + q * 128 + k;
      int n = idx >> 7, c = idx & 127;
      W2T[n * 128 + c] = f2h(W2[c * 64 + n]);
    }
  }
}

// ---- main: one block per agent i; 4 waves = 2(j-half) x 2(n-half) ----
__global__ __launch_bounds__(256, 4) void pool_main(
    const unsigned short* __restrict__ Ah,    // (1024,128) f16
    const float* __restrict__ M2f,            // (2,128) f32
    const float* __restrict__ track,          // (1024,8,2) f32
    const unsigned short* __restrict__ W2T,   // (64,128) f16
    const float* __restrict__ b2,             // (64) f32
    float* __restrict__ out)                  // (1024,64) f32
{
  const int i    = blockIdx.x;
  const int lane = threadIdx.x & 63;
  const int wv   = threadIdx.x >> 6;
  const int wn   = wv & 1;      // n-half: cols [wn*32, wn*32+32)
  const int wj   = wv >> 1;     // j-half: tiles jt = wj + 2*t, t=0..31
  const int m    = lane & 15;   // A row within tile / B-and-D column
  const int quad = lane >> 4;   // k-subrange selector

  const int STEP = 2 * 16 * 128;   // elems between this wave's consecutive tiles
  const unsigned short* Ap = Ah + (wj * 16 + m) * 128 + quad * 8;

  // double-buffered A-row loads (tiles t=0,1 of this wave)
  uintx4 bufA[4], bufB[4];
#pragma unroll
  for (int kk = 0; kk < 4; ++kk) bufA[kk] = *(const uintx4*)(Ap + kk * 32);
#pragma unroll
  for (int kk = 0; kk < 4; ++kk) bufB[kk] = *(const uintx4*)(Ap + STEP + kk * 32);

  // U[i] as packed f16 pairs, matching A's dword element order
  const float e0 = track[i * 16 + 14];
  const float e1 = track[i * 16 + 15];
  unsigned upk[4][4];
#pragma unroll
  for (int kk = 0; kk < 4; ++kk) {
#pragma unroll
    for (int p = 0; p < 4; ++p) {
      int k0 = kk * 32 + quad * 8 + 2 * p;
      float a = e0 * M2f[k0]     + e1 * M2f[128 + k0];
      float b = e0 * M2f[k0 + 1] + e1 * M2f[128 + k0 + 1];
      upk[kk][p] = (unsigned)f2h(a) | ((unsigned)f2h(b) << 16);
    }
  }

  // this wave's 32-col B panel (2 x 16-col blocks), register-resident: 32 VGPR
  half8 bfrag[2][4];
#pragma unroll
  for (int tb = 0; tb < 2; ++tb)
#pragma unroll
    for (int kk = 0; kk < 4; ++kk)
      bfrag[tb][kk] = *(const half8*)(W2T + ((wn * 2 + tb) * 16 + m) * 128 + kk * 32 + quad * 8);

  floatx4 mx[2];
#pragma unroll
  for (int tb = 0; tb < 2; ++tb) mx[tb] = (floatx4){-3e38f, -3e38f, -3e38f, -3e38f};

#pragma unroll
  for (int t = 0; t < 32; t += 2) {
    // ---- tile t (bufA); prefetch tile t+2 ----
    {
      uintx4 au[4];
#pragma unroll
      for (int kk = 0; kk < 4; ++kk)
#pragma unroll
        for (int p = 0; p < 4; ++p) au[kk][p] = pk_sub_relu(bufA[kk][p], upk[kk][p]);
      if (t + 2 < 32) {
        const unsigned short* p2 = Ap + (t + 2) * STEP;
#pragma unroll
        for (int kk = 0; kk < 4; ++kk) bufA[kk] = *(const uintx4*)(p2 + kk * 32);
      }
#pragma unroll
      for (int tb = 0; tb < 2; ++tb) {
        floatx4 acc = (floatx4){0.f, 0.f, 0.f, 0.f};
#pragma unroll
        for (int kk = 0; kk < 4; ++kk)
          acc = __builtin_amdgcn_mfma_f32_16x16x32_f16(
              __builtin_bit_cast(half8, au[kk]), bfrag[tb][kk], acc, 0, 0, 0);
#pragma unroll
        for (int r = 0; r < 4; ++r) mx[tb][r] = fmaxf(mx[tb][r], acc[r]);
      }
    }
    // ---- tile t+1 (bufB); prefetch tile t+3 ----
    {
      uintx4 au[4];
#pragma unroll
      for (int kk = 0; kk < 4; ++kk)
#pragma unroll
        for (int p = 0; p < 4; ++p) au[kk][p] = pk_sub_relu(bufB[kk][p], upk[kk][p]);
      if (t + 3 < 32) {
        const unsigned short* p2 = Ap + (t + 3) * STEP;
#pragma unroll
        for (int kk = 0; kk < 4; ++kk) bufB[kk] = *(const uintx4*)(p2 + kk * 32);
      }
#pragma unroll
      for (int tb = 0; tb < 2; ++tb) {
        floatx4 acc = (floatx4){0.f, 0.f, 0.f, 0.f};
#pragma unroll
        for (int kk = 0; kk < 4; ++kk)
          acc = __builtin_amdgcn_mfma_f32_16x16x32_f16(
              __builtin_bit_cast(half8, au[kk]), bfrag[tb][kk], acc, 0, 0, 0);
#pragma unroll
        for (int r = 0; r < 4; ++r) mx[tb][r] = fmaxf(mx[tb][r], acc[r]);
      }
    }
  }

  // D layout: row = quad*4 + r (j within tile), col = m. Reduce rows in-lane, then across quads,
  // then across the two wj waves via LDS. Cols are disjoint across wn.
  float lm[2];
#pragma unroll
  for (int tb = 0; tb < 2; ++tb) {
    lm[tb] = fmaxf(fmaxf(mx[tb][0], mx[tb][1]), fmaxf(mx[tb][2], mx[tb][3]));
    lm[tb] = fmaxf(lm[tb], __shfl_xor(lm[tb], 16, 64));
    lm[tb] = fmaxf(lm[tb], __shfl_xor(lm[tb], 32, 64));
  }
  __shared__ float red[2][64];
  if (quad == 0) {
#pragma unroll
    for (int tb = 0; tb < 2; ++tb) red[wj][(wn * 2 + tb) * 16 + m] = lm[tb];
  }
  __syncthreads();
  if (threadIdx.x < 64) {
    int n = threadIdx.x;
    float v = fmaxf(red[0][n], red[1][n]);
    v += b2[n];
    v = v > 0.f ? v : 0.f;
    out[i * 64 + n] = v;
  }
}

extern "C" void kernel_launch(void* const* d_in, const int* in_sizes, int n_in,
                              void* d_out, int out_size, void* d_ws, size_t ws_size,
                              hipStream_t stream) {
  const float* hidden = (const float*)d_in[0]; // (1,1024,64)
  const float* track  = (const float*)d_in[1]; // (1024,8,2)
  const float* We     = (const float*)d_in[2]; // (2,16)
  const float* be     = (const float*)d_in[3]; // (16)
  const float* W1     = (const float*)d_in[4]; // (80,128)
  const float* b1     = (const float*)d_in[5]; // (128)
  const float* W2     = (const float*)d_in[6]; // (128,64)
  const float* b2     = (const float*)d_in[7]; // (64)
  float* out = (float*)d_out;

  char* ws = (char*)d_ws;
  unsigned short* Ah  = (unsigned short*)ws;              // 1024*128*2 = 256 KiB
  float*          M2f = (float*)(ws + 262144);            // 256*4     = 1 KiB
  unsigned short* W2T = (unsigned short*)(ws + 263168);   // 64*128*2  = 16 KiB

  prep_all<<<N_AG, 128, 0, stream>>>(hidden, track, We, be, W1, b1, W2, Ah, M2f, W2T);
  pool_main<<<N_AG, 256, 0, stream>>>(Ah, M2f, track, W2T, b2, out);
}

// Round 4
// 133.565 us; speedup vs baseline: 1.0523x; 1.0523x over previous
//
#include <hip/hip_runtime.h>

// SGAN_PoolingNet: pooled[i] = max_j relu( relu([hidden[j], (ends[j]-ends[i])@We+be] @ W1 + b1) @ W2 + b2 )
// Collapse: y_lin[i,j,:] = A[j,:] - U[i,:]
//   A[j,k] = hidden[j]@W1[0:64,k] + ends[j]@M2[:,k] + b1[k] + be@W1[64:80,k]   (f32 math, stored f16)
//   U[i,k] = ends[i]@M2[:,k],  M2 = We @ W1[64:80,:]  (2x128, f32)
// R7: R6 spilled (launch_bounds(256,4): 128-reg cap vs ~120-reg demand + full unroll ->
//     VGPR_Count 64, WRITE_SIZE 44 MB of scratch, 80 us). Fix the budget arithmetic:
//  (a) __launch_bounds__(256,3): cap 170 regs -> no spill, guaranteed >=3 waves/SIMD
//      (vs R2's 2); compiler may still hit 4 if alloc <=128.
//  (b) t-loop NOT unrolled (pragma unroll 1): dbuf body already covers 2 tiles; bounded live set.
//  (c) keep f16 packed datapath (v_pk_add_f16 neg + v_pk_max_f16: 2 instr/dword) and
//      2(j)x2(n) wave split (bfrag = 32 VGPR).
//  (d) prep_all: 4 j-rows per block (256 blocks) -> W1 re-read 40 MB -> 10 MB, 4x FMA per load.

#define N_AG 1024
#define JT 4

typedef __attribute__((ext_vector_type(8))) _Float16 half8;      // 8 f16 = 4 VGPR (MFMA A/B frag)
typedef __attribute__((ext_vector_type(4))) float floatx4;       // MFMA C/D frag
typedef __attribute__((ext_vector_type(4))) unsigned int uintx4; // 4 packed f16 pairs

__device__ __forceinline__ unsigned short f2h(float f) {
  return __builtin_bit_cast(unsigned short, (_Float16)f);   // RNE
}

// d = max(a - u, 0) elementwise on packed f16 pairs: 2 VALU instrs, no unpack.
__device__ __forceinline__ unsigned pk_sub_relu(unsigned a, unsigned u) {
  unsigned d;
  asm("v_pk_add_f16 %0, %1, %2 neg_lo:[0,1] neg_hi:[0,1]\n\t"
      "v_pk_max_f16 %0, %0, 0"
      : "=v"(d) : "v"(a), "v"(u));
  return d;
}

// ---- prep: block jb computes A[4jb..4jb+3]; block 0 writes M2; blocks 0..31 write W2T ----
__global__ __launch_bounds__(128) void prep_all(
    const float* __restrict__ hidden,  // (1,1024,64)
    const float* __restrict__ track,   // (1024,8,2)
    const float* __restrict__ We,      // (2,16)
    const float* __restrict__ be,      // (16)
    const float* __restrict__ W1,      // (80,128)
    const float* __restrict__ b1,      // (128)
    const float* __restrict__ W2,      // (128,64)
    unsigned short* __restrict__ Ah,   // (1024,128) f16
    float* __restrict__ M2f,           // (2,128) f32
    unsigned short* __restrict__ W2T)  // (64,128) f16
{
  const int jb = blockIdx.x;          // 0..255
  const int j0 = jb * JT;
  const int k  = threadIdx.x;         // 0..127
  __shared__ float hs[JT][64];
#pragma unroll
  for (int q = k; q < JT * 64; q += 128) hs[q >> 6][q & 63] = hidden[j0 * 64 + q];
  __syncthreads();

  float m20 = 0.f, m21 = 0.f, cb = b1[k];
#pragma unroll
  for (int t = 0; t < 16; ++t) {
    float w1v = W1[(64 + t) * 128 + k];
    m20 += We[t] * w1v;
    m21 += We[16 + t] * w1v;
    cb  += be[t] * w1v;
  }
  float acc[JT];
#pragma unroll
  for (int jj = 0; jj < JT; ++jj) {
    float e0 = track[(j0 + jj) * 16 + 14];
    float e1 = track[(j0 + jj) * 16 + 15];
    acc[jj] = e0 * m20 + e1 * m21 + cb;
  }
#pragma unroll 8
  for (int t = 0; t < 64; ++t) {
    float w = W1[t * 128 + k];
#pragma unroll
    for (int jj = 0; jj < JT; ++jj) acc[jj] += hs[jj][t] * w;
  }
#pragma unroll
  for (int jj = 0; jj < JT; ++jj)
    __builtin_nontemporal_store(f2h(acc[jj]), &Ah[(j0 + jj) * 128 + k]);

  if (jb == 0) {          // m20/m21 are exactly M2[0][k], M2[1][k]
    M2f[k]       = m20;
    M2f[128 + k] = m21;
  }
  if (jb < 32) {          // W2T[n][c] = f16(W2[c][n]); 32 blocks x 256 entries
#pragma unroll
    for (int q = 0; q < 2; ++q) {
      int idx = jb * 256 + q * 128 + k;
      int n = idx >> 7, c = idx & 127;
      W2T[n * 128 + c] = f2h(W2[c * 64 + n]);
    }
  }
}

// ---- main: one block per agent i; 4 waves = 2(j-half) x 2(n-half) ----
__global__ __launch_bounds__(256, 3) void pool_main(
    const unsigned short* __restrict__ Ah,    // (1024,128) f16
    const float* __restrict__ M2f,            // (2,128) f32
    const float* __restrict__ track,          // (1024,8,2) f32
    const unsigned short* __restrict__ W2T,   // (64,128) f16
    const float* __restrict__ b2,             // (64) f32
    float* __restrict__ out)                  // (1024,64) f32
{
  const int i    = blockIdx.x;
  const int lane = threadIdx.x & 63;
  const int wv   = threadIdx.x >> 6;
  const int wn   = wv & 1;      // n-half: cols [wn*32, wn*32+32)
  const int wj   = wv >> 1;     // j-half: tiles jt = wj + 2*t, t=0..31
  const int m    = lane & 15;   // A row within tile / B-and-D column
  const int quad = lane >> 4;   // k-subrange selector

  const int STEP = 2 * 16 * 128;   // elems between this wave's consecutive tiles
  const unsigned short* Ap = Ah + (wj * 16 + m) * 128 + quad * 8;

  // double-buffered A-row loads (tiles t=0,1 of this wave) — issue ASAP
  uintx4 bufA[4], bufB[4];
#pragma unroll
  for (int kk = 0; kk < 4; ++kk) bufA[kk] = *(const uintx4*)(Ap + kk * 32);
#pragma unroll
  for (int kk = 0; kk < 4; ++kk) bufB[kk] = *(const uintx4*)(Ap + STEP + kk * 32);

  // U[i] as packed f16 pairs, matching A's dword element order
  const float e0 = track[i * 16 + 14];
  const float e1 = track[i * 16 + 15];
  unsigned upk[4][4];
#pragma unroll
  for (int kk = 0; kk < 4; ++kk) {
#pragma unroll
    for (int p = 0; p < 4; ++p) {
      int k0 = kk * 32 + quad * 8 + 2 * p;
      float a = e0 * M2f[k0]     + e1 * M2f[128 + k0];
      float b = e0 * M2f[k0 + 1] + e1 * M2f[128 + k0 + 1];
      upk[kk][p] = (unsigned)f2h(a) | ((unsigned)f2h(b) << 16);
    }
  }

  // this wave's 32-col B panel (2 x 16-col blocks), register-resident: 32 VGPR
  half8 bfrag[2][4];
#pragma unroll
  for (int tb = 0; tb < 2; ++tb)
#pragma unroll
    for (int kk = 0; kk < 4; ++kk)
      bfrag[tb][kk] = *(const half8*)(W2T + ((wn * 2 + tb) * 16 + m) * 128 + kk * 32 + quad * 8);

  floatx4 mx[2];
#pragma unroll
  for (int tb = 0; tb < 2; ++tb) mx[tb] = (floatx4){-3e38f, -3e38f, -3e38f, -3e38f};

#pragma unroll 1
  for (int t = 0; t < 32; t += 2) {
    // ---- tile t (bufA); prefetch tile t+2 ----
    {
      uintx4 au[4];
#pragma unroll
      for (int kk = 0; kk < 4; ++kk)
#pragma unroll
        for (int p = 0; p < 4; ++p) au[kk][p] = pk_sub_relu(bufA[kk][p], upk[kk][p]);
      if (t + 2 < 32) {
        const unsigned short* p2 = Ap + (t + 2) * STEP;
#pragma unroll
        for (int kk = 0; kk < 4; ++kk) bufA[kk] = *(const uintx4*)(p2 + kk * 32);
      }
#pragma unroll
      for (int tb = 0; tb < 2; ++tb) {
        floatx4 acc = (floatx4){0.f, 0.f, 0.f, 0.f};
#pragma unroll
        for (int kk = 0; kk < 4; ++kk)
          acc = __builtin_amdgcn_mfma_f32_16x16x32_f16(
              __builtin_bit_cast(half8, au[kk]), bfrag[tb][kk], acc, 0, 0, 0);
#pragma unroll
        for (int r = 0; r < 4; ++r) mx[tb][r] = fmaxf(mx[tb][r], acc[r]);
      }
    }
    // ---- tile t+1 (bufB); prefetch tile t+3 ----
    {
      uintx4 au[4];
#pragma unroll
      for (int kk = 0; kk < 4; ++kk)
#pragma unroll
        for (int p = 0; p < 4; ++p) au[kk][p] = pk_sub_relu(bufB[kk][p], upk[kk][p]);
      if (t + 3 < 32) {
        const unsigned short* p2 = Ap + (t + 3) * STEP;
#pragma unroll
        for (int kk = 0; kk < 4; ++kk) bufB[kk] = *(const uintx4*)(p2 + kk * 32);
      }
#pragma unroll
      for (int tb = 0; tb < 2; ++tb) {
        floatx4 acc = (floatx4){0.f, 0.f, 0.f, 0.f};
#pragma unroll
        for (int kk = 0; kk < 4; ++kk)
          acc = __builtin_amdgcn_mfma_f32_16x16x32_f16(
              __builtin_bit_cast(half8, au[kk]), bfrag[tb][kk], acc, 0, 0, 0);
#pragma unroll
        for (int r = 0; r < 4; ++r) mx[tb][r] = fmaxf(mx[tb][r], acc[r]);
      }
    }
  }

  // D layout: row = quad*4 + r (j within tile), col = m. Reduce rows in-lane, then across quads,
  // then across the two wj waves via LDS. Cols are disjoint across wn.
  float lm[2];
#pragma unroll
  for (int tb = 0; tb < 2; ++tb) {
    lm[tb] = fmaxf(fmaxf(mx[tb][0], mx[tb][1]), fmaxf(mx[tb][2], mx[tb][3]));
    lm[tb] = fmaxf(lm[tb], __shfl_xor(lm[tb], 16, 64));
    lm[tb] = fmaxf(lm[tb], __shfl_xor(lm[tb], 32, 64));
  }
  __shared__ float red[2][64];
  if (quad == 0) {
#pragma unroll
    for (int tb = 0; tb < 2; ++tb) red[wj][(wn * 2 + tb) * 16 + m] = lm[tb];
  }
  __syncthreads();
  if (threadIdx.x < 64) {
    int n = threadIdx.x;
    float v = fmaxf(red[0][n], red[1][n]);
    v += b2[n];
    v = v > 0.f ? v : 0.f;
    out[i * 64 + n] = v;
  }
}

extern "C" void kernel_launch(void* const* d_in, const int* in_sizes, int n_in,
                              void* d_out, int out_size, void* d_ws, size_t ws_size,
                              hipStream_t stream) {
  const float* hidden = (const float*)d_in[0]; // (1,1024,64)
  const float* track  = (const float*)d_in[1]; // (1024,8,2)
  const float* We     = (const float*)d_in[2]; // (2,16)
  const float* be     = (const float*)d_in[3]; // (16)
  const float* W1     = (const float*)d_in[4]; // (80,128)
  const float* b1     = (const float*)d_in[5]; // (128)
  const float* W2     = (const float*)d_in[6]; // (128,64)
  const float* b2     = (const float*)d_in[7]; // (64)
  float* out = (float*)d_out;

  char* ws = (char*)d_ws;
  unsigned short* Ah  = (unsigned short*)ws;              // 1024*128*2 = 256 KiB
  float*          M2f = (float*)(ws + 262144);            // 256*4     = 1 KiB
  unsigned short* W2T = (unsigned short*)(ws + 263168);   // 64*128*2  = 16 KiB

  prep_all<<<N_AG / JT, 128, 0, stream>>>(hidden, track, We, be, W1, b1, W2, Ah, M2f, W2T);
  pool_main<<<N_AG, 256, 0, stream>>>(Ah, M2f, track, W2T, b2, out);
}

// Round 5
// 92.169 us; speedup vs baseline: 1.5250x; 1.4491x over previous
//
#include <hip/hip_runtime.h>

// SGAN_PoolingNet: pooled[i] = max_j relu( relu([hidden[j], (ends[j]-ends[i])@We+be] @ W1 + b1) @ W2 + b2 )
// Collapse: y_lin[i,j,:] = A[j,:] - U[i,:]
//   A[j,k] = hidden[j]@W1[0:64,k] + ends[j]@M2[:,k] + b1[k] + be@W1[64:80,k]   (f32 math, stored f16)
//   U[i,k] = ends[i]@M2[:,k],  M2 = We @ W1[64:80,:]  (2x128, f32)
// R8: R7 counters: VALU 15%, MFMA 9%, HBM 0.3% -> ~80% memory-latency stall. The 2jx2n split
//     DOUBLED per-wave A loads (each row read by both wn waves) on a latency-bound kernel
//     (stall 24us -> 58us). Fix by raising arithmetic intensity per load, not duplicating:
//  (a) G=2 agents per block (grid 512): each A tile loaded ONCE, used for 2 repacks + 32 MFMAs
//      (~360cy compute per 4 loads); L2 traffic halves (256->128 MB).
//  (b) waves back to disjoint-j (4-way, 16 tiles each), full 64-col bfrag (64 regs, AGPR-able).
//  (c) depth-2 register ring, static slots (named buf0/buf1), load issued mid-body -> ~500cy
//      coverage; no barriers in loop so compiler emits counted vmcnt, never vmcnt(0).
//  (d) __launch_bounds__(256,2): demand ~200 unified regs < 256 cap -> NO spill (R6 lesson);
//      2 blocks/CU x 256 CU = 512 = grid -> single fully-resident round, no tail round.

#define N_AG 1024
#define JT 4

typedef __attribute__((ext_vector_type(8))) _Float16 half8;      // 8 f16 = 4 VGPR (MFMA A/B frag)
typedef __attribute__((ext_vector_type(4))) float floatx4;       // MFMA C/D frag
typedef __attribute__((ext_vector_type(4))) unsigned int uintx4; // 4 packed f16 pairs

__device__ __forceinline__ unsigned short f2h(float f) {
  return __builtin_bit_cast(unsigned short, (_Float16)f);   // RNE
}

// d = max(a - u, 0) elementwise on packed f16 pairs: 2 VALU instrs, no unpack.
__device__ __forceinline__ unsigned pk_sub_relu(unsigned a, unsigned u) {
  unsigned d;
  asm("v_pk_add_f16 %0, %1, %2 neg_lo:[0,1] neg_hi:[0,1]\n\t"
      "v_pk_max_f16 %0, %0, 0"
      : "=v"(d) : "v"(a), "v"(u));
  return d;
}

// ---- prep: block jb computes A[4jb..4jb+3]; block 0 writes M2; blocks 0..31 write W2T ----
__global__ __launch_bounds__(128) void prep_all(
    const float* __restrict__ hidden,  // (1,1024,64)
    const float* __restrict__ track,   // (1024,8,2)
    const float* __restrict__ We,      // (2,16)
    const float* __restrict__ be,      // (16)
    const float* __restrict__ W1,      // (80,128)
    const float* __restrict__ b1,      // (128)
    const float* __restrict__ W2,      // (128,64)
    unsigned short* __restrict__ Ah,   // (1024,128) f16
    float* __restrict__ M2f,           // (2,128) f32
    unsigned short* __restrict__ W2T)  // (64,128) f16
{
  const int jb = blockIdx.x;          // 0..255
  const int j0 = jb * JT;
  const int k  = threadIdx.x;         // 0..127
  __shared__ float hs[JT][64];
#pragma unroll
  for (int q = k; q < JT * 64; q += 128) hs[q >> 6][q & 63] = hidden[j0 * 64 + q];
  __syncthreads();

  float m20 = 0.f, m21 = 0.f, cb = b1[k];
#pragma unroll
  for (int t = 0; t < 16; ++t) {
    float w1v = W1[(64 + t) * 128 + k];
    m20 += We[t] * w1v;
    m21 += We[16 + t] * w1v;
    cb  += be[t] * w1v;
  }
  float acc[JT];
#pragma unroll
  for (int jj = 0; jj < JT; ++jj) {
    float e0 = track[(j0 + jj) * 16 + 14];
    float e1 = track[(j0 + jj) * 16 + 15];
    acc[jj] = e0 * m20 + e1 * m21 + cb;
  }
#pragma unroll 8
  for (int t = 0; t < 64; ++t) {
    float w = W1[t * 128 + k];
#pragma unroll
    for (int jj = 0; jj < JT; ++jj) acc[jj] += hs[jj][t] * w;
  }
#pragma unroll
  for (int jj = 0; jj < JT; ++jj)
    __builtin_nontemporal_store(f2h(acc[jj]), &Ah[(j0 + jj) * 128 + k]);

  if (jb == 0) {          // m20/m21 are exactly M2[0][k], M2[1][k]
    M2f[k]       = m20;
    M2f[128 + k] = m21;
  }
  if (jb < 32) {          // W2T[n][c] = f16(W2[c][n]); 32 blocks x 256 entries
#pragma unroll
    for (int q = 0; q < 2; ++q) {
      int idx = jb * 256 + q * 128 + k;
      int n = idx >> 7, c = idx & 127;
      W2T[n * 128 + c] = f2h(W2[c * 64 + n]);
    }
  }
}

// ---- main: one block per 2 agents; 4 waves split j 4-way (disjoint), each full 64 cols ----
__global__ __launch_bounds__(256, 2) void pool_main(
    const unsigned short* __restrict__ Ah,    // (1024,128) f16
    const float* __restrict__ M2f,            // (2,128) f32
    const float* __restrict__ track,          // (1024,8,2) f32
    const unsigned short* __restrict__ W2T,   // (64,128) f16
    const float* __restrict__ b2,             // (64) f32
    float* __restrict__ out)                  // (1024,64) f32
{
  const int i0   = blockIdx.x * 2;
  const int lane = threadIdx.x & 63;
  const int w    = threadIdx.x >> 6;   // wave 0..3: j-tiles jt = 4t + w
  const int m    = lane & 15;          // A row within tile / B-and-D column
  const int quad = lane >> 4;          // k-subrange selector

  const int TSTEP = 4 * 16 * 128;      // elems between this wave's consecutive tiles
  const unsigned short* base = Ah + (w * 16 + m) * 128 + quad * 8;

  // depth-2 register ring: issue tiles 0,1 of this wave ASAP
  uintx4 buf0[4], buf1[4];
#pragma unroll
  for (int kk = 0; kk < 4; ++kk) buf0[kk] = *(const uintx4*)(base + kk * 32);
#pragma unroll
  for (int kk = 0; kk < 4; ++kk) buf1[kk] = *(const uintx4*)(base + TSTEP + kk * 32);

  // U[i0], U[i0+1] as packed f16 pairs matching A's dword element order
  const float a0 = track[i0 * 16 + 14];
  const float a1 = track[i0 * 16 + 15];
  const float c0 = track[(i0 + 1) * 16 + 14];
  const float c1 = track[(i0 + 1) * 16 + 15];
  unsigned upkA[4][4], upkB[4][4];
#pragma unroll
  for (int kk = 0; kk < 4; ++kk) {
#pragma unroll
    for (int p = 0; p < 4; ++p) {
      int k0 = kk * 32 + quad * 8 + 2 * p;
      float m0 = M2f[k0],     m0h = M2f[128 + k0];
      float m1 = M2f[k0 + 1], m1h = M2f[128 + k0 + 1];
      upkA[kk][p] = (unsigned)f2h(a0 * m0 + a1 * m0h) | ((unsigned)f2h(a0 * m1 + a1 * m1h) << 16);
      upkB[kk][p] = (unsigned)f2h(c0 * m0 + c1 * m0h) | ((unsigned)f2h(c0 * m1 + c1 * m1h) << 16);
    }
  }

  // full 64-col B panel per wave (4 x 16-col blocks), register/AGPR-resident
  half8 bfrag[4][4];
#pragma unroll
  for (int nt = 0; nt < 4; ++nt)
#pragma unroll
    for (int kk = 0; kk < 4; ++kk)
      bfrag[nt][kk] = *(const half8*)(W2T + (nt * 16 + m) * 128 + kk * 32 + quad * 8);

  floatx4 mxA[4], mxB[4];
#pragma unroll
  for (int nt = 0; nt < 4; ++nt) {
    mxA[nt] = (floatx4){-3e38f, -3e38f, -3e38f, -3e38f};
    mxB[nt] = (floatx4){-3e38f, -3e38f, -3e38f, -3e38f};
  }

  const unsigned short* pn = base + 2 * TSTEP;   // next tile to load (t+2)

#define POOL_BODY(BUF, DO_LOAD)                                               \
  {                                                                           \
    uintx4 au[4];                                                             \
    _Pragma("unroll") for (int kk = 0; kk < 4; ++kk)                          \
      _Pragma("unroll") for (int p = 0; p < 4; ++p)                           \
        au[kk][p] = pk_sub_relu(BUF[kk][p], upkA[kk][p]);                     \
    _Pragma("unroll") for (int nt = 0; nt < 4; ++nt) {                        \
      floatx4 acc = (floatx4){0.f, 0.f, 0.f, 0.f};                            \
      _Pragma("unroll") for (int kk = 0; kk < 4; ++kk)                        \
        acc = __builtin_amdgcn_mfma_f32_16x16x32_f16(                         \
            __builtin_bit_cast(half8, au[kk]), bfrag[nt][kk], acc, 0, 0, 0);  \
      _Pragma("unroll") for (int r = 0; r < 4; ++r)                           \
        mxA[nt][r] = fmaxf(mxA[nt][r], acc[r]);                               \
    }                                                                         \
    _Pragma("unroll") for (int kk = 0; kk < 4; ++kk)                          \
      _Pragma("unroll") for (int p = 0; p < 4; ++p)                           \
        au[kk][p] = pk_sub_relu(BUF[kk][p], upkB[kk][p]);                     \
    if (DO_LOAD) {                                                            \
      _Pragma("unroll") for (int kk = 0; kk < 4; ++kk)                        \
        BUF[kk] = *(const uintx4*)(pn + kk * 32);                             \
      pn += TSTEP;                                                            \
    }                                                                         \
    _Pragma("unroll") for (int nt = 0; nt < 4; ++nt) {                        \
      floatx4 acc = (floatx4){0.f, 0.f, 0.f, 0.f};                            \
      _Pragma("unroll") for (int kk = 0; kk < 4; ++kk)                        \
        acc = __builtin_amdgcn_mfma_f32_16x16x32_f16(                         \
            __builtin_bit_cast(half8, au[kk]), bfrag[nt][kk], acc, 0, 0, 0);  \
      _Pragma("unroll") for (int r = 0; r < 4; ++r)                           \
        mxB[nt][r] = fmaxf(mxB[nt][r], acc[r]);                               \
    }                                                                         \
  }

#pragma unroll 1
  for (int t2 = 0; t2 < 14; t2 += 2) {
    POOL_BODY(buf0, true)
    POOL_BODY(buf1, true)
  }
  POOL_BODY(buf0, false)   // t=14
  POOL_BODY(buf1, false)   // t=15
#undef POOL_BODY

  // D layout: row = quad*4 + r (j within tile), col = nt*16 + m. Reduce rows in-lane,
  // across quads via shfl, across the 4 j-waves via LDS. Two agents' results side by side.
  __shared__ float red[2][4][64];
#pragma unroll
  for (int nt = 0; nt < 4; ++nt) {
    float a = fmaxf(fmaxf(mxA[nt][0], mxA[nt][1]), fmaxf(mxA[nt][2], mxA[nt][3]));
    a = fmaxf(a, __shfl_xor(a, 16, 64));
    a = fmaxf(a, __shfl_xor(a, 32, 64));
    float b = fmaxf(fmaxf(mxB[nt][0], mxB[nt][1]), fmaxf(mxB[nt][2], mxB[nt][3]));
    b = fmaxf(b, __shfl_xor(b, 16, 64));
    b = fmaxf(b, __shfl_xor(b, 32, 64));
    if (quad == 0) {
      red[0][w][nt * 16 + m] = a;
      red[1][w][nt * 16 + m] = b;
    }
  }
  __syncthreads();
  if (threadIdx.x < 128) {
    int g = threadIdx.x >> 6, n = threadIdx.x & 63;
    float v = fmaxf(fmaxf(red[g][0][n], red[g][1][n]), fmaxf(red[g][2][n], red[g][3][n]));
    v += b2[n];
    out[(i0 + g) * 64 + n] = v > 0.f ? v : 0.f;
  }
}

extern "C" void kernel_launch(void* const* d_in, const int* in_sizes, int n_in,
                              void* d_out, int out_size, void* d_ws, size_t ws_size,
                              hipStream_t stream) {
  const float* hidden = (const float*)d_in[0]; // (1,1024,64)
  const float* track  = (const float*)d_in[1]; // (1024,8,2)
  const float* We     = (const float*)d_in[2]; // (2,16)
  const float* be     = (const float*)d_in[3]; // (16)
  const float* W1     = (const float*)d_in[4]; // (80,128)
  const float* b1     = (const float*)d_in[5]; // (128)
  const float* W2     = (const float*)d_in[6]; // (128,64)
  const float* b2     = (const float*)d_in[7]; // (64)
  float* out = (float*)d_out;

  char* ws = (char*)d_ws;
  unsigned short* Ah  = (unsigned short*)ws;              // 1024*128*2 = 256 KiB
  float*          M2f = (float*)(ws + 262144);            // 256*4     = 1 KiB
  unsigned short* W2T = (unsigned short*)(ws + 263168);   // 64*128*2  = 16 KiB

  prep_all<<<N_AG / JT, 128, 0, stream>>>(hidden, track, We, be, W1, b1, W2, Ah, M2f, W2T);
  pool_main<<<N_AG / 2, 256, 0, stream>>>(Ah, M2f, track, W2T, b2, out);
}